// Round 1
// baseline (992.709 us; speedup 1.0000x reference)
//
#include <hip/hip_runtime.h>
#include <hip/hip_bf16.h>
#include <math.h>

typedef __attribute__((ext_vector_type(8))) __bf16 bf16x8;
typedef __attribute__((ext_vector_type(4))) float floatx4;
typedef __attribute__((ext_vector_type(8))) unsigned short ushort8v;

__device__ inline unsigned short f2u(float f) {
  __hip_bfloat16 h = __float2bfloat16(f);
  unsigned short u;
  __builtin_memcpy(&u, &h, 2);
  return u;
}

__device__ inline floatx4 mfma16(bf16x8 a, bf16x8 b, floatx4 c) {
  return __builtin_amdgcn_mfma_f32_16x16x32_bf16(a, b, c, 0, 0, 0);
}

__device__ inline void gload_lds16(const unsigned short* g, unsigned short* l) {
  __builtin_amdgcn_global_load_lds(
      (__attribute__((address_space(1))) void*)g,
      (__attribute__((address_space(3))) void*)l,
      16, 0, 0);
}

// ---------------- cast fp32 -> bf16 (vectorized) ----------------
__global__ __launch_bounds__(256) void castk(const float* __restrict__ in,
                                             unsigned short* __restrict__ out,
                                             int n4) {
  int i = blockIdx.x * 256 + threadIdx.x;
  if (i >= n4) return;
  const float4 v = reinterpret_cast<const float4*>(in)[i];
  ushort4 o;
  o.x = f2u(v.x);
  o.y = f2u(v.y);
  o.z = f2u(v.z);
  o.w = f2u(v.w);
  reinterpret_cast<ushort4*>(out)[i] = o;
}

// ---------------- GEMM: C[m,n] = sum_k A[m,k] * B[n,k]  (both row-major, K inner) ----
// 128x128 tile, BK=32, 4 waves (2x2), 4x4 16x16x32 bf16 MFMA frags per wave.
template <int OUT_F32>
__global__ __launch_bounds__(256)
void gemm_bt(const unsigned short* __restrict__ A,
             const unsigned short* __restrict__ B,
             unsigned short* __restrict__ Cb,
             float* __restrict__ Cf,
             const float* __restrict__ bias,
             int M, int N, int K) {
  __shared__ unsigned short Asm_[128 * 32];
  __shared__ unsigned short Bsm_[128 * 32];
  const int t = threadIdx.x;
  const int w = t >> 6;
  const int l = t & 63;
  const int m0 = blockIdx.y * 128;
  const int n0 = blockIdx.x * 128;
  const int wm = w >> 1, wn = w & 1;

  // staging: per wave w, call c in {0,1}: LDS elems [(w*2+c)*512, +512)
  // lane l covers elems +l*8 .. +7 -> row (w*32 + c*16 + l/4), col (l&3)*8
  const int srow = l >> 2;
  const int scol = (l & 3) * 8;
  const unsigned short* gA = A + (size_t)(m0 + w * 32 + srow) * K + scol;
  const unsigned short* gB = B + (size_t)(n0 + w * 32 + srow) * K + scol;
  unsigned short* lA = &Asm_[w * 1024];
  unsigned short* lB = &Bsm_[w * 1024];

  floatx4 acc[4][4];
#pragma unroll
  for (int i = 0; i < 4; i++)
#pragma unroll
    for (int j = 0; j < 4; j++) acc[i][j] = (floatx4){0.f, 0.f, 0.f, 0.f};

  const int fr = l & 15;
  const int fk = (l >> 4) * 8;

  for (int k0 = 0; k0 < K; k0 += 32) {
    gload_lds16(gA + k0, lA);
    gload_lds16(gA + (size_t)16 * K + k0, lA + 512);
    gload_lds16(gB + k0, lB);
    gload_lds16(gB + (size_t)16 * K + k0, lB + 512);
    __syncthreads();

    bf16x8 af[4], bfr[4];
#pragma unroll
    for (int i = 0; i < 4; i++)
      af[i] = *reinterpret_cast<const bf16x8*>(&Asm_[(wm * 64 + i * 16 + fr) * 32 + fk]);
#pragma unroll
    for (int j = 0; j < 4; j++)
      bfr[j] = *reinterpret_cast<const bf16x8*>(&Bsm_[(wn * 64 + j * 16 + fr) * 32 + fk]);
#pragma unroll
    for (int i = 0; i < 4; i++)
#pragma unroll
      for (int j = 0; j < 4; j++) acc[i][j] = mfma16(af[i], bfr[j], acc[i][j]);
    __syncthreads();
  }

  const int er = (l >> 4) * 4;
  const int ec = l & 15;
#pragma unroll
  for (int i = 0; i < 4; i++) {
#pragma unroll
    for (int j = 0; j < 4; j++) {
      const int col = n0 + wn * 64 + j * 16 + ec;
#pragma unroll
      for (int r = 0; r < 4; r++) {
        const int row = m0 + wm * 64 + i * 16 + er + r;
        if (OUT_F32) {
          Cf[(size_t)row * N + col] = acc[i][j][r] + bias[col];
        } else {
          Cb[(size_t)row * N + col] = f2u(acc[i][j][r]);
        }
      }
    }
  }
}

// ---------------- flash attention ----------------
// Y: (8192 x 6144) bf16, cols [0,2048)=Q [2048,4096)=K [4096,6144)=V, head h at +h*128.
// Block: 4 waves x 16 q-rows = 64 q-rows. KV tile = 32.
__global__ __launch_bounds__(256)
void attn_kernel(const unsigned short* __restrict__ Y,
                 unsigned short* __restrict__ att) {
  __shared__ unsigned short Vt[128 * 32];   // [dh][kvrow]
  __shared__ unsigned short Pl[4][16 * 32]; // per-wave P tile [qrow][kvcol]

  const int t = threadIdx.x;
  const int w = t >> 6;
  const int l = t & 63;
  const int bid = blockIdx.x;
  const int bh = bid & 63;  // bh-fastest: all q-tiles of one (b,h) share XCD L2
  const int qt = bid >> 6;
  const int b = bh >> 4;
  const int h = bh & 15;

  const size_t base = (size_t)b * 2048 * 6144 + (size_t)h * 128;
  const unsigned short* Qp = Y + base;
  const unsigned short* Kp = Y + base + 2048;
  const unsigned short* Vp = Y + base + 4096;

  const int fr = l & 15;
  const int fkb = l >> 4;

  const int qrow = qt * 64 + w * 16 + fr;
  bf16x8 qf[4];
#pragma unroll
  for (int kk = 0; kk < 4; kk++)
    qf[kk] = *reinterpret_cast<const bf16x8*>(
        &Qp[(size_t)qrow * 6144 + kk * 32 + fkb * 8]);

  floatx4 oacc[8];
#pragma unroll
  for (int nt = 0; nt < 8; nt++) oacc[nt] = (floatx4){0.f, 0.f, 0.f, 0.f};
  float mrun[4], lrun[4];
#pragma unroll
  for (int r = 0; r < 4; r++) {
    mrun[r] = -INFINITY;
    lrun[r] = 0.f;
  }

  const int vkr = t >> 3;
  const int vd0 = (t & 7) * 16;
  const float sscale = 0.08838834764831845f;  // 1/sqrt(128)

  for (int kv = 0; kv < 2048; kv += 32) {
    __syncthreads();  // prior iter's Vt reads complete before overwrite
    {
      const unsigned short* vrow = &Vp[(size_t)(kv + vkr) * 6144 + vd0];
      ushort8v v0 = *reinterpret_cast<const ushort8v*>(vrow);
      ushort8v v1 = *reinterpret_cast<const ushort8v*>(vrow + 8);
#pragma unroll
      for (int j = 0; j < 8; j++) Vt[(vd0 + j) * 32 + vkr] = v0[j];
#pragma unroll
      for (int j = 0; j < 8; j++) Vt[(vd0 + 8 + j) * 32 + vkr] = v1[j];
    }
    __syncthreads();

    // S = Q K^T for 16 q-rows x 32 kv-cols
    floatx4 sacc[2];
    sacc[0] = (floatx4){0.f, 0.f, 0.f, 0.f};
    sacc[1] = (floatx4){0.f, 0.f, 0.f, 0.f};
#pragma unroll
    for (int nt = 0; nt < 2; nt++) {
#pragma unroll
      for (int kk = 0; kk < 4; kk++) {
        bf16x8 kf = *reinterpret_cast<const bf16x8*>(
            &Kp[(size_t)(kv + nt * 16 + fr) * 6144 + kk * 32 + fkb * 8]);
        sacc[nt] = mfma16(qf[kk], kf, sacc[nt]);
      }
    }

    // online softmax, per reg r (q-row = fkb*4+r), reduce over 16-lane group
#pragma unroll
    for (int r = 0; r < 4; r++) {
      float s0 = sacc[0][r] * sscale;
      float s1 = sacc[1][r] * sscale;
      float mx = fmaxf(s0, s1);
      mx = fmaxf(mx, __shfl_xor(mx, 1));
      mx = fmaxf(mx, __shfl_xor(mx, 2));
      mx = fmaxf(mx, __shfl_xor(mx, 4));
      mx = fmaxf(mx, __shfl_xor(mx, 8));
      float mn = fmaxf(mrun[r], mx);
      float alpha = __expf(mrun[r] - mn);
      float p0 = __expf(s0 - mn);
      float p1 = __expf(s1 - mn);
      float ps = p0 + p1;
      ps += __shfl_xor(ps, 1);
      ps += __shfl_xor(ps, 2);
      ps += __shfl_xor(ps, 4);
      ps += __shfl_xor(ps, 8);
      lrun[r] = lrun[r] * alpha + ps;
      mrun[r] = mn;
#pragma unroll
      for (int nt = 0; nt < 8; nt++) oacc[nt][r] *= alpha;
      const int prow = fkb * 4 + r;
      Pl[w][prow * 32 + fr] = f2u(p0);
      Pl[w][prow * 32 + 16 + fr] = f2u(p1);
    }

    // PV: out(16 x 128) += P(16x32) @ V(32x128); same-wave LDS round-trip
    bf16x8 pf = *reinterpret_cast<const bf16x8*>(&Pl[w][fr * 32 + fkb * 8]);
#pragma unroll
    for (int nt = 0; nt < 8; nt++) {
      bf16x8 vf = *reinterpret_cast<const bf16x8*>(
          &Vt[(nt * 16 + fr) * 32 + fkb * 8]);
      oacc[nt] = mfma16(pf, vf, oacc[nt]);
    }
  }

  // epilogue: att[(b*2048+row)*2048 + h*128 + dh] = oacc / lsum
#pragma unroll
  for (int nt = 0; nt < 8; nt++) {
#pragma unroll
    for (int r = 0; r < 4; r++) {
      const int row = qt * 64 + w * 16 + fkb * 4 + r;
      const size_t midx = ((size_t)b * 2048 + row) * 2048 + h * 128 + nt * 16 + fr;
      att[midx] = f2u(oacc[nt][r] / lrun[r]);
    }
  }
}

// ---------------- launch ----------------
extern "C" void kernel_launch(void* const* d_in, const int* in_sizes, int n_in,
                              void* d_out, int out_size, void* d_ws, size_t ws_size,
                              hipStream_t stream) {
  const float* x = (const float*)d_in[0];
  const float* wq = (const float*)d_in[1];
  const float* wk = (const float*)d_in[2];
  const float* wv = (const float*)d_in[3];
  const float* wo = (const float*)d_in[4];
  const float* bo = (const float*)d_in[5];

  unsigned short* ws = (unsigned short*)d_ws;
  unsigned short* x16 = ws;                       // 16,777,216
  unsigned short* wqkv16 = x16 + 16777216;        // 12,582,912
  unsigned short* wo16 = wqkv16 + 12582912;       // 4,194,304
  unsigned short* Y16 = wo16 + 4194304;           // 50,331,648
  unsigned short* att16 = Y16 + 50331648;         // 16,777,216
  // total 192 MB

  castk<<<16384, 256, 0, stream>>>(x, x16, 4194304);
  castk<<<4096, 256, 0, stream>>>(wq, wqkv16, 1048576);
  castk<<<4096, 256, 0, stream>>>(wk, wqkv16 + 4194304, 1048576);
  castk<<<4096, 256, 0, stream>>>(wv, wqkv16 + 8388608, 1048576);
  castk<<<4096, 256, 0, stream>>>(wo, wo16, 1048576);

  dim3 g1(48, 64);
  gemm_bt<0><<<g1, 256, 0, stream>>>(x16, wqkv16, Y16, nullptr, nullptr,
                                     8192, 6144, 2048);

  attn_kernel<<<2048, 256, 0, stream>>>(Y16, att16);

  dim3 g2(16, 64);
  gemm_bt<1><<<g2, 256, 0, stream>>>(att16, wo16, nullptr, (float*)d_out, bo,
                                     8192, 2048, 2048);
}